// Round 2
// baseline (194.254 us; speedup 1.0000x reference)
//
#include <hip/hip_runtime.h>

#define H_IN 128
#define W_IN 128
#define H_OUT 64
#define W_OUT 64

__device__ __forceinline__ float tri_mu(float v, float c) {
    // matches reference: clip(1 - |v - c| / 1.5, 0, None)
    return fmaxf(1.0f - fabsf(v - c) / 1.5f, 0.0f);
}

__device__ __forceinline__ float fuzzy4(float p0, float p1, float p2, float p3) {
    // Reference fuzzy sets (NOTE: mu2 and mu3 are IDENTICAL — both center 3.0,
    // width 1.5 — because reference passes _R=3.0 as mu3's center. So argmax
    // over (s1,s2,s3) with first-index tie-break reduces to: s1>=s2 ? set1 : set2.)
    float a0 = tri_mu(p0, 1.5f), a1 = tri_mu(p1, 1.5f), a2 = tri_mu(p2, 1.5f), a3 = tri_mu(p3, 1.5f);
    float b0 = tri_mu(p0, 3.0f), b1 = tri_mu(p1, 3.0f), b2 = tri_mu(p2, 3.0f), b3 = tri_mu(p3, 3.0f);

    float s1 = ((a0 + a1) + a2) + a3;
    float s2 = ((b0 + b1) + b2) + b3;

    float u0, u1, u2, u3;
    if (s1 >= s2) {
        u0 = a0; u1 = a1; u2 = a2; u3 = a3;
    } else {
        u0 = b0; u1 = b1; u2 = b2; u3 = b3;
    }

    // num = sum((mu*p)*p), den = sum(mu*p), sequential K-order
    float t0 = u0 * p0, t1 = u1 * p1, t2 = u2 * p2, t3 = u3 * p3;
    float num = ((t0 * p0 + t1 * p1) + t2 * p2) + t3 * p3;
    float den = ((t0 + t1) + t2) + t3;
    return (den == 0.0f) ? 0.0f : num / den;
}

// Each thread handles 2 adjacent output pixels in one output row:
//   loads float4 from input rows 2*ho and 2*ho+1, writes float2 to output.
__global__ __launch_bounds__(256) void fuzzy_pool_kernel(
        const float* __restrict__ x, float* __restrict__ out, int n_pairs) {
    int gid = blockIdx.x * blockDim.x + threadIdx.x;
    if (gid >= n_pairs) return;

    int row = gid >> 5;          // 32 float4-pairs per output row (W_OUT/2)
    int pw  = gid & 31;
    int bc  = row >> 6;          // row / H_OUT
    int ho  = row & 63;          // row % H_OUT

    const float* r0 = x + (size_t)bc * (H_IN * W_IN) + (size_t)(2 * ho) * W_IN + pw * 4;
    const float* r1 = r0 + W_IN;

    float4 top = *(const float4*)r0;
    float4 bot = *(const float4*)r1;

    float2 o;
    // patch order: p = [x[2ho,2wo], x[2ho,2wo+1], x[2ho+1,2wo], x[2ho+1,2wo+1]]
    o.x = fuzzy4(top.x, top.y, bot.x, bot.y);
    o.y = fuzzy4(top.z, top.w, bot.z, bot.w);

    *(float2*)(out + (size_t)row * W_OUT + pw * 2) = o;
}

extern "C" void kernel_launch(void* const* d_in, const int* in_sizes, int n_in,
                              void* d_out, int out_size, void* d_ws, size_t ws_size,
                              hipStream_t stream) {
    const float* x = (const float*)d_in[0];
    float* out = (float*)d_out;

    int n_pairs = out_size / 2;            // 4,194,304
    int block = 256;
    int grid = (n_pairs + block - 1) / block;
    fuzzy_pool_kernel<<<grid, block, 0, stream>>>(x, out, n_pairs);
}

// Round 4
// 186.127 us; speedup vs baseline: 1.0437x; 1.0437x over previous
//
#include <hip/hip_runtime.h>

#define H_IN 128
#define W_IN 128
#define H_OUT 64
#define W_OUT 64

// native vector type — __builtin_nontemporal_* requires scalar/pointer/ext-vector,
// not HIP_vector_type (a class)
typedef float vf4 __attribute__((ext_vector_type(4)));

// tri(v,c) = clip(1 - |v-c|/1.5, 0, inf)  -- computed as fma with 2/3 (exact-div
// replacement is safe: absmax threshold 9e-2, observed error 1.6e-2)
__device__ __forceinline__ float tri_mu(float v, float c) {
    return fmaxf(fmaf(fabsf(v - c), -0.66666666666666667f, 1.0f), 0.0f);
}

__device__ __forceinline__ float fuzzy4(float p0, float p1, float p2, float p3) {
    // Reference fuzzy sets: mu2 and mu3 are IDENTICAL (both center 3.0, width
    // 1.5 — reference passes _R=3.0 as mu3's center). argmax with first-index
    // tie-break reduces to: s1>=s2 ? set1 : set2.
    float a0 = tri_mu(p0, 1.5f), a1 = tri_mu(p1, 1.5f), a2 = tri_mu(p2, 1.5f), a3 = tri_mu(p3, 1.5f);
    float b0 = tri_mu(p0, 3.0f), b1 = tri_mu(p1, 3.0f), b2 = tri_mu(p2, 3.0f), b3 = tri_mu(p3, 3.0f);

    float s1 = ((a0 + a1) + a2) + a3;
    float s2 = ((b0 + b1) + b2) + b3;

    bool sel1 = (s1 >= s2);
    float u0 = sel1 ? a0 : b0;
    float u1 = sel1 ? a1 : b1;
    float u2 = sel1 ? a2 : b2;
    float u3 = sel1 ? a3 : b3;

    float t0 = u0 * p0, t1 = u1 * p1, t2 = u2 * p2, t3 = u3 * p3;
    float num = ((t0 * p0 + t1 * p1) + t2 * p2) + t3 * p3;
    float den = ((t0 + t1) + t2) + t3;
    // hardware rcp (~1 ulp) instead of exact div; den==0 handled explicitly
    float r = __builtin_amdgcn_rcpf(den);
    return (den == 0.0f) ? 0.0f : num * r;
}

// Each thread computes 4 adjacent output pixels in one output row:
//   loads 2x 16B from input rows 2*ho and 2*ho+1 (32 B/row), writes one
//   16B vector to output. All accesses 16B-aligned and coalesced.
__global__ __launch_bounds__(256) void fuzzy_pool_kernel(
        const float* __restrict__ x, float* __restrict__ out, int n_quads) {
    int gid = blockIdx.x * blockDim.x + threadIdx.x;
    if (gid >= n_quads) return;

    int row = gid >> 4;          // 16 output-quads per output row (W_OUT/4)
    int qw  = gid & 15;
    int bc  = row >> 6;          // row / H_OUT
    int ho  = row & 63;          // row % H_OUT

    const float* r0 = x + (size_t)bc * (H_IN * W_IN) + (size_t)(2 * ho) * W_IN + qw * 8;
    const float* r1 = r0 + W_IN;

    vf4 ta = __builtin_nontemporal_load((const vf4*)r0);
    vf4 tb = __builtin_nontemporal_load((const vf4*)r0 + 1);
    vf4 ba = __builtin_nontemporal_load((const vf4*)r1);
    vf4 bb = __builtin_nontemporal_load((const vf4*)r1 + 1);

    vf4 o;
    // patch order: p = [x[2ho,2wo], x[2ho,2wo+1], x[2ho+1,2wo], x[2ho+1,2wo+1]]
    o.x = fuzzy4(ta.x, ta.y, ba.x, ba.y);
    o.y = fuzzy4(ta.z, ta.w, ba.z, ba.w);
    o.z = fuzzy4(tb.x, tb.y, bb.x, bb.y);
    o.w = fuzzy4(tb.z, tb.w, bb.z, bb.w);

    __builtin_nontemporal_store(o, (vf4*)(out + (size_t)row * W_OUT + qw * 4));
}

extern "C" void kernel_launch(void* const* d_in, const int* in_sizes, int n_in,
                              void* d_out, int out_size, void* d_ws, size_t ws_size,
                              hipStream_t stream) {
    const float* x = (const float*)d_in[0];
    float* out = (float*)d_out;

    int n_quads = out_size / 4;            // 2,097,152
    int block = 256;
    int grid = (n_quads + block - 1) / block;   // 8192 blocks
    fuzzy_pool_kernel<<<grid, block, 0, stream>>>(x, out, n_quads);
}